// Round 17
// baseline (166.674 us; speedup 1.0000x reference)
//
#include <hip/hip_runtime.h>
#include <math.h>

#define CIN   256
#define COUT  256
#define H     64
#define W     64
#define HW    4096
#define KK    9
#define KC    2304
#define NOFF  27
#define B_    4
#define EPS   1e-5f
#define OM3S  (B_ * NOFF * HW)   // floats per offconv partial buffer

typedef __attribute__((ext_vector_type(4))) float f32x4;
typedef __attribute__((ext_vector_type(8))) short s16x8;

static __device__ __forceinline__ unsigned short f2bf(float f) {
  unsigned u = __builtin_bit_cast(unsigned, f);
  u += 0x7FFF + ((u >> 16) & 1);
  return (unsigned short)(u >> 16);
}
static __device__ __forceinline__ float bflo(unsigned u) {
  return __builtin_bit_cast(float, u << 16);
}
static __device__ __forceinline__ float bfhi(unsigned u) {
  return __builtin_bit_cast(float, u & 0xffff0000u);
}
static __device__ __forceinline__ unsigned packbf(float lo, float hi) {
  unsigned ul = __builtin_bit_cast(unsigned, lo);
  unsigned uh = __builtin_bit_cast(unsigned, hi);
  ul += 0x7FFF + ((ul >> 16) & 1);
  uh += 0x7FFF + ((uh >> 16) & 1);
  return (ul >> 16) | (uh & 0xffff0000u);
}

// ---------------------------------------------------------------------------
// prep: fused xprep + weight prep + gstat zero. (verified R5/R9/R12)
// ---------------------------------------------------------------------------
__global__ __launch_bounds__(256) void prep_kernel(
    const float* __restrict__ x, const float* __restrict__ w,
    const float* __restrict__ w_off, unsigned short* __restrict__ xT,
    unsigned short* __restrict__ wBf, unsigned short* __restrict__ wOBf,
    float* __restrict__ gstat) {
  int bi = blockIdx.x;
  int t = threadIdx.x;
  if (bi < 256) {
    __shared__ unsigned short tile[64][272];
    int b = bi >> 6, y = bi & 63;
    const float* src = x + (size_t)b * CIN * HW + y * W;
    for (int r = 0; r < 64; ++r) {
      int idx = r * 256 + t;
      int c = idx >> 6, ww = idx & 63;
      tile[ww][c] = f2bf(src[(size_t)c * HW + ww]);
    }
    __syncthreads();
    unsigned short* dst = xT + ((size_t)(b * 64 + y) * 64) * 256;
    for (int r = 0; r < 8; ++r) {
      int idx = r * 2048 + t * 8;
      int ww = idx >> 8, c = idx & 255;
      *(uint4*)(dst + idx) = *(const uint4*)&tile[ww][c];
    }
  } else if (bi < 544) {
    int pkt = (bi - 256) * 256 + t;        // [0, 73728)
    int lane = pkt & 63;
    int tn = (pkt >> 6) & 15;
    int k2 = pkt >> 10;
    int co = tn * 16 + (lane & 15);
    int kb = k2 * 32 + (lane >> 4) * 8;
    unsigned short v[8];
#pragma unroll
    for (int j = 0; j < 8; ++j) {
      int kk = kb + j;
      int kt = kk >> 8, c = kk & 255;
      v[j] = f2bf(w[(co * 256 + c) * 9 + kt]);
    }
    *(uint4*)&wBf[(size_t)pkt * 8] = *(const uint4*)v;
  } else if (bi < 580) {
    int pkt = (bi - 544) * 256 + t;        // [0, 9216)
    int lane = pkt & 63;
    int tn = (pkt >> 6) & 1;
    int k2 = pkt >> 7;
    int oc = tn * 16 + (lane & 15);
    int kb = k2 * 32 + (lane >> 4) * 8;
    unsigned short v[8];
#pragma unroll
    for (int j = 0; j < 8; ++j) {
      int kk = kb + j;
      int kt = kk >> 8, c = kk & 255;
      v[j] = (oc < NOFF) ? f2bf(w_off[(oc * 256 + c) * 9 + kt]) : (unsigned short)0;
    }
    *(uint4*)&wOBf[(size_t)pkt * 8] = *(const uint4*)v;
  } else {
    if (t < 128) gstat[t] = 0.f;
  }
}

// ---------------------------------------------------------------------------
// offconv: tap-split x3 partials, no LDS/barriers. grid 768. (verified)
// ---------------------------------------------------------------------------
__global__ __launch_bounds__(256) void offconv_mfma_kernel(
    const unsigned short* __restrict__ xT, const unsigned short* __restrict__ wOBf,
    float* __restrict__ om3) {
  int bi = blockIdx.x;
  int ts = bi >> 8;
  int row = bi & 255;
  int b = row >> 6, i = row & 63;
  int t = threadIdx.x, lane = t & 63, wv = t >> 6;
  int lr = lane & 15, lq = lane >> 4;
  int p = wv * 16 + lr;
  const unsigned short* xb = xT + (size_t)b * (HW * 256);
  f32x4 acc[2] = {};

  for (int kc = 0; kc < 3; ++kc) {
    int kt = ts * 3 + kc;
    int ky = kt / 3, kx = kt % 3;
    int yy = i - 1 + ky, xx = p - 1 + kx;
    bool ok = ((unsigned)yy < 64u) && ((unsigned)xx < 64u);
    const unsigned short* ap = xb + ((ok ? yy * 64 + xx : 0) << 8) + lq * 8;
#pragma unroll
    for (int c8 = 0; c8 < 8; ++c8) {
      uint4 av = uint4{0, 0, 0, 0};
      if (ok) av = *(const uint4*)(ap + c8 * 32);
      int k2 = kt * 8 + c8;
      s16x8 a = __builtin_bit_cast(s16x8, av);
      s16x8 b0 = *(const s16x8*)(wOBf + ((((k2 * 2 + 0) << 6) | lane) << 3));
      s16x8 b1 = *(const s16x8*)(wOBf + ((((k2 * 2 + 1) << 6) | lane) << 3));
      acc[0] = __builtin_amdgcn_mfma_f32_16x16x32_bf16(a, b0, acc[0], 0, 0, 0);
      acc[1] = __builtin_amdgcn_mfma_f32_16x16x32_bf16(a, b1, acc[1], 0, 0, 0);
    }
  }
#pragma unroll
  for (int tn = 0; tn < 2; ++tn) {
    int oc = tn * 16 + lr;
    if (oc < NOFF) {
      float* ob = om3 + (size_t)ts * OM3S + ((b * NOFF + oc) << 12) + i * 64 + wv * 16;
#pragma unroll
      for (int r = 0; r < 4; ++r) ob[lq * 4 + r] = acc[tn][r];
    }
  }
}

// ---------------------------------------------------------------------------
// gemm_fused: producer/consumer wave specialization (R14 base, 65.7us) +
// XCD-AWARE BLOCK SWIZZLE (T1). R14's 1600cyc/phase fixed cost traced to
// gather L2-miss: FETCH 28.9MB >> 14MB inputs because round-robin
// block->XCD assignment spreads all 4 images over every XCD (8MB of xb
// per 4MB L2 -> thrash -> ~900cyc HBM gather tail > 1-phase cover).
// Swizzle mt = ((bid&7)<<5)|(bid>>3): XCD x (=bid&7) gets 32 consecutive
// m-tiles = ONE image's xb (2MB, L2-resident). Bijective (grid 256).
// R16's merged-phase experiment reverted (it removed the 1-phase gather
// cover and regressed). Everything else identical to R14.
// ---------------------------------------------------------------------------
__global__ __launch_bounds__(512, 2) void gemm_fused_kernel(
    const unsigned short* __restrict__ xT, const float* __restrict__ om3,
    const float* __restrict__ b_off, const unsigned short* __restrict__ wBf,
    const float* __restrict__ bias, unsigned short* __restrict__ cvt,
    float* __restrict__ gstat) {
  __shared__ float tapw[64][KK][4];           // 9.2 KB
  __shared__ int   tapc[64][KK][4];           // 9.2 KB
  __shared__ unsigned short At[2][64 * 64];   // 2 x 8 KB, row pitch 128 B
  int bid = blockIdx.x;
  int mt = ((bid & 7) << 5) | (bid >> 3);     // XCD swizzle: XCD = bid&7
  int m0 = mt * 64;
  int b = m0 >> 12;
  int irow = (m0 & 4095) >> 6;                // image row (fixed per tile)
  int t = threadIdx.x;                        // 0..511
  int lane = t & 63, wv = t >> 6;             // wv 0..7
  int lr = lane & 15, lq = lane >> 4;
  const unsigned short* xb = xT + (size_t)b * (HW * 256);

  // ---- tap tables: 64 pixels x 9 taps (once per block, 512 threads) ----
  for (int idx = t; idx < 64 * KK; idx += 512) {
    int p = idx / KK, k = idx % KK;
    int pix = (m0 & 4095) + p;
    size_t o = (size_t)(b * NOFF) * HW + pix;
    float offy = om3[o + k * HW] + om3[OM3S + o + k * HW] +
                 om3[2 * OM3S + o + k * HW] + b_off[k];
    float offx = om3[o + (9 + k) * HW] + om3[OM3S + o + (9 + k) * HW] +
                 om3[2 * OM3S + o + (9 + k) * HW] + b_off[9 + k];
    float mval = om3[o + (18 + k) * HW] + om3[OM3S + o + (18 + k) * HW] +
                 om3[2 * OM3S + o + (18 + k) * HW] + b_off[18 + k];
    float mask = 1.f / (1.f + __expf(-mval));
    float py = (float)(irow - 1 + k / 3) + offy;
    float px = (float)(p - 1 + k % 3) + offx;
    float y0f = floorf(py), x0f = floorf(px);
    float wy1 = py - y0f, wx1 = px - x0f;
    int y0 = (int)y0f, x0 = (int)x0f;
    bool y0ok = (unsigned)y0 < 64u, y1ok = (unsigned)(y0 + 1) < 64u;
    bool x0ok = (unsigned)x0 < 64u, x1ok = (unsigned)(x0 + 1) < 64u;
    tapw[p][k][0] = (1.f - wy1) * (1.f - wx1) * mask * (float)(y0ok && x0ok);
    tapw[p][k][1] = (1.f - wy1) * wx1 * mask * (float)(y0ok && x1ok);
    tapw[p][k][2] = wy1 * (1.f - wx1) * mask * (float)(y1ok && x0ok);
    tapw[p][k][3] = wy1 * wx1 * mask * (float)(y1ok && x1ok);
    int y0c = min(max(y0, 0), 63), y1c = min(max(y0 + 1, 0), 63);
    int x0c = min(max(x0, 0), 63), x1c = min(max(x0 + 1, 0), 63);
    tapc[p][k][0] = (y0c * 64 + x0c) * 256;
    tapc[p][k][1] = (x1c - x0c) * 256;
    tapc[p][k][2] = (y1c - y0c) * 64 * 256;
    tapc[p][k][3] = 0;
  }
  __syncthreads();

  // roles: waves 0-3 produce, waves 4-7 consume.
  bool isProd = (wv < 4);
  // producer mapping (threads 0..255): row p = t>>2, octet pair q = t&3
  int p = (t & 255) >> 2, q = t & 3;
  // consumer mapping: cw = wv-4 -> cout block cw*64
  int cw = isProd ? 0 : (wv - 4);
  const unsigned short* bb = wBf + ((size_t)(cw * 4) * 64 + lane) * 8;
  // B addr for (k2, tn): bb + k2*8192 + tn*512

  f32x4 acc[4][4] = {};
  s16x8 Bfa[2][4], Bfb[2][4];
  uint4 sG[8];

#define GLOAD(JJ)                                                            \
  {                                                                          \
    int kt_ = (JJ) >> 2, cg_ = (JJ) & 3;                                     \
    int4 tc_ = *(const int4*)&tapc[p][kt_][0];                               \
    const unsigned short* c_ = xb + tc_.x + cg_ * 64 + q * 16;               \
    sG[0] = *(const uint4*)(c_);                                             \
    sG[1] = *(const uint4*)(c_ + 8);                                         \
    sG[2] = *(const uint4*)(c_ + tc_.y);                                     \
    sG[3] = *(const uint4*)(c_ + tc_.y + 8);                                 \
    sG[4] = *(const uint4*)(c_ + tc_.z);                                     \
    sG[5] = *(const uint4*)(c_ + tc_.z + 8);                                 \
    sG[6] = *(const uint4*)(c_ + tc_.z + tc_.y);                             \
    sG[7] = *(const uint4*)(c_ + tc_.z + tc_.y + 8);                         \
  }

#define COMBINE(JJ, BUFI)                                                    \
  {                                                                          \
    int kt_ = (JJ) >> 2;                                                     \
    f32x4 tw_ = *(const f32x4*)&tapw[p][kt_][0];                             \
    _Pragma("unroll") for (int o = 0; o < 2; ++o) {                          \
      const unsigned* a00_ = (const unsigned*)&sG[0 + o];                    \
      const unsigned* a01_ = (const unsigned*)&sG[2 + o];                    \
      const unsigned* a10_ = (const unsigned*)&sG[4 + o];                    \
      const unsigned* a11_ = (const unsigned*)&sG[6 + o];                    \
      uint4 res_;                                                            \
      unsigned* rr_ = (unsigned*)&res_;                                      \
      _Pragma("unroll") for (int u = 0; u < 4; ++u) {                        \
        float lo_ = tw_[0] * bflo(a00_[u]) + tw_[1] * bflo(a01_[u]) +        \
                    tw_[2] * bflo(a10_[u]) + tw_[3] * bflo(a11_[u]);         \
        float hi_ = tw_[0] * bfhi(a00_[u]) + tw_[1] * bfhi(a01_[u]) +        \
                    tw_[2] * bfhi(a10_[u]) + tw_[3] * bfhi(a11_[u]);         \
        rr_[u] = packbf(lo_, hi_);                                           \
      }                                                                      \
      *(uint4*)((char*)At[BUFI] + p * 128 + (((q * 2 + o) ^ (p & 7)) * 16)) = res_; \
    }                                                                        \
  }

#define BISSUE(J, SLOT)                                                      \
  {                                                                          \
    int k2b_ = (J) * 2;                                                      \
    _Pragma("unroll") for (int kh = 0; kh < 2; ++kh)                         \
      _Pragma("unroll") for (int tn = 0; tn < 4; ++tn)                       \
        SLOT[kh][tn] = *(const s16x8*)(bb + (size_t)(k2b_ + kh) * 8192 + tn * 512); \
  }

#define CONSUME(BUFI, SLOT)                                                  \
  {                                                                          \
    const char* buf_ = (const char*)At[BUFI];                                \
    _Pragma("unroll") for (int kh = 0; kh < 2; ++kh) {                       \
      s16x8 af[4];                                                           \
      _Pragma("unroll") for (int tm = 0; tm < 4; ++tm) {                     \
        int r_ = tm * 16 + lr;                                               \
        af[tm] = *(const s16x8*)(buf_ + r_ * 128 + (((kh * 4 + lq) ^ (r_ & 7)) * 16)); \
      }                                                                      \
      __builtin_amdgcn_s_setprio(1);                                         \
      _Pragma("unroll") for (int tm = 0; tm < 4; ++tm)                       \
        _Pragma("unroll") for (int tn = 0; tn < 4; ++tn)                     \
          acc[tm][tn] = __builtin_amdgcn_mfma_f32_16x16x32_bf16(             \
              af[tm], SLOT[kh][tn], acc[tm][tn], 0, 0, 0);                   \
      __builtin_amdgcn_s_setprio(0);                                         \
    }                                                                        \
  }

#define SOFTBAR()                                                            \
  {                                                                          \
    asm volatile("s_waitcnt lgkmcnt(0)" ::: "memory");                       \
    __builtin_amdgcn_sched_barrier(0);                                       \
    __builtin_amdgcn_s_barrier();                                            \
  }

  // prologue: producers build A(0) into buf0 and issue gathers(1);
  // consumers prefetch B(0)/B(1). Barrier is uniform.
  if (isProd) {
    GLOAD(0);
    COMBINE(0, 0);             // vmcnt auto-wait on gathers(0)
    GLOAD(1);
  } else {
    BISSUE(0, Bfa);
    BISSUE(1, Bfb);
  }
  SOFTBAR();                   // buf0 visible; gathers(1) stay in flight

#pragma unroll 1
  for (int k = 0; k < 36; k += 2) {
    // ---- phase k: producers build k+1 into buf1; consumers eat buf0 ----
    if (isProd) {
      COMBINE(k + 1, 1);                   // k+1 <= 35 always
      if (k + 2 < 36) GLOAD(k + 2);
    } else {
      CONSUME(0, Bfa);
      if (k + 2 < 36) BISSUE(k + 2, Bfa);
    }
    SOFTBAR();
    // ---- phase k+1: producers build k+2 into buf0; consumers eat buf1 ----
    if (isProd) {
      if (k + 2 < 36) COMBINE(k + 2, 0);
      if (k + 3 < 36) GLOAD(k + 3);
    } else {
      CONSUME(1, Bfb);
      if (k + 3 < 36) BISSUE(k + 3, Bfb);
    }
    SOFTBAR();
  }

#undef GLOAD
#undef COMBINE
#undef BISSUE
#undef CONSUME
#undef SOFTBAR

  // epilogue (consumers only, barrier-free):
  // m = m0 + tm*16 + lq*4 + r, co = cw*64 + tn*16 + lr
  if (!isProd) {
    int poff = m0 & 4095;
#pragma unroll
    for (int tn = 0; tn < 4; ++tn) {
      int co = cw * 64 + tn * 16 + lr;
      float bco = bias[co];
      unsigned short* cvb = cvt + (size_t)(b * COUT + co) * HW + poff;
      float sS = 0.f, qq = 0.f;
#pragma unroll
      for (int tm = 0; tm < 4; ++tm) {
        ushort4 st;
#pragma unroll
        for (int r = 0; r < 4; ++r) {
          float v = acc[tm][tn][r] + bco;
          sS += v;
          qq += v * v;
          ((unsigned short*)&st)[r] = f2bf(v);
        }
        *(ushort4*)(cvb + tm * 16 + lq * 4) = st;
      }
#pragma unroll
      for (int off = 32; off > 0; off >>= 1) {
        sS += __shfl_down(sS, off, 64);
        qq += __shfl_down(qq, off, 64);
      }
      if (lane == 0) {
        int g = co >> 4;
        atomicAdd(&gstat[(b * 16 + g) * 2 + 0], sS);
        atomicAdd(&gstat[(b * 16 + g) * 2 + 1], qq);
      }
    }
  }
}

// ---------------------------------------------------------------------------
// gn_apply: normalize bf16 convout -> f32 out. grid 2048. (verified)
// ---------------------------------------------------------------------------
__global__ __launch_bounds__(256) void gn_apply_kernel(
    const unsigned short* __restrict__ convout, const float* __restrict__ gstat,
    const float* __restrict__ gamma, const float* __restrict__ beta,
    float* __restrict__ out) {
  int vid = blockIdx.x * 256 + threadIdx.x;
  int e = vid * 8;
  int b = e >> 20;
  int c = (e >> 12) & 255;
  int g = c >> 4;
  float S = gstat[(b * 16 + g) * 2 + 0];
  float Q = gstat[(b * 16 + g) * 2 + 1];
  float mu = S * (1.f / 65536.f);
  float var = Q * (1.f / 65536.f) - mu * mu;
  float rs = rsqrtf(var + EPS);
  float a = rs * gamma[c];
  float bb = beta[c] - mu * a;
  uint4 v = *(const uint4*)(convout + e);
  const unsigned* u = (const unsigned*)&v;
  float4 o0, o1;
  o0.x = bflo(u[0]) * a + bb;  o0.y = bfhi(u[0]) * a + bb;
  o0.z = bflo(u[1]) * a + bb;  o0.w = bfhi(u[1]) * a + bb;
  o1.x = bflo(u[2]) * a + bb;  o1.y = bfhi(u[2]) * a + bb;
  o1.z = bflo(u[3]) * a + bb;  o1.w = bfhi(u[3]) * a + bb;
  *(float4*)(out + e) = o0;
  *(float4*)(out + e + 4) = o1;
}

// ---------------------------------------------------------------------------
extern "C" void kernel_launch(void* const* d_in, const int* in_sizes, int n_in,
                              void* d_out, int out_size, void* d_ws, size_t ws_size,
                              hipStream_t stream) {
  const float* x      = (const float*)d_in[0];
  const float* w_off  = (const float*)d_in[1];
  const float* b_off  = (const float*)d_in[2];
  const float* weight = (const float*)d_in[3];
  const float* bias   = (const float*)d_in[4];
  const float* gamma  = (const float*)d_in[5];
  const float* beta   = (const float*)d_in[6];
  float* out = (float*)d_out;

  // ws layout: om3 | xT | wBf | wOBf | cvt | gstat
  // cvt must NOT alias xT (fused gemm reads xT while writing cvt).
  float* om3 = (float*)d_ws;                                  // 5.31 MB
  unsigned short* xT   = (unsigned short*)(om3 + (size_t)3 * OM3S);  // 8.39 MB
  unsigned short* wBf  = xT + (size_t)B_ * HW * 256;          // 1.18 MB
  unsigned short* wOBf = wBf + (size_t)COUT * KC;             // 147 KB
  unsigned short* cvt  = wOBf + (size_t)32 * KC;              // 8.39 MB (ex-Abuf)
  float* gstat = (float*)(cvt + (size_t)B_ * HW * COUT);      // 512 B

  prep_kernel<<<dim3(581), dim3(256), 0, stream>>>(x, weight, w_off, xT, wBf, wOBf, gstat);
  offconv_mfma_kernel<<<dim3(768), dim3(256), 0, stream>>>(xT, wOBf, om3);
  gemm_fused_kernel<<<dim3(256), dim3(512), 0, stream>>>(xT, om3, b_off, wBf, bias, cvt, gstat);
  gn_apply_kernel<<<dim3(2048), dim3(256), 0, stream>>>(cvt, gstat, gamma, beta, out);
}

// Round 18
// 162.954 us; speedup vs baseline: 1.0228x; 1.0228x over previous
//
#include <hip/hip_runtime.h>
#include <math.h>

#define CIN   256
#define COUT  256
#define H     64
#define W     64
#define HW    4096
#define KK    9
#define KC    2304
#define NOFF  27
#define B_    4
#define EPS   1e-5f

typedef __attribute__((ext_vector_type(4))) float f32x4;
typedef __attribute__((ext_vector_type(8))) short s16x8;

static __device__ __forceinline__ unsigned short f2bf(float f) {
  unsigned u = __builtin_bit_cast(unsigned, f);
  u += 0x7FFF + ((u >> 16) & 1);
  return (unsigned short)(u >> 16);
}
static __device__ __forceinline__ float bflo(unsigned u) {
  return __builtin_bit_cast(float, u << 16);
}
static __device__ __forceinline__ float bfhi(unsigned u) {
  return __builtin_bit_cast(float, u & 0xffff0000u);
}
static __device__ __forceinline__ unsigned packbf(float lo, float hi) {
  unsigned ul = __builtin_bit_cast(unsigned, lo);
  unsigned uh = __builtin_bit_cast(unsigned, hi);
  ul += 0x7FFF + ((ul >> 16) & 1);
  uh += 0x7FFF + ((uh >> 16) & 1);
  return (ul >> 16) | (uh & 0xffff0000u);
}

// ---------------------------------------------------------------------------
// prep: fused xprep + weight prep + gstat zero. (verified R5/R9/R12)
// ---------------------------------------------------------------------------
__global__ __launch_bounds__(256) void prep_kernel(
    const float* __restrict__ x, const float* __restrict__ w,
    const float* __restrict__ w_off, unsigned short* __restrict__ xT,
    unsigned short* __restrict__ wBf, unsigned short* __restrict__ wOBf,
    float* __restrict__ gstat) {
  int bi = blockIdx.x;
  int t = threadIdx.x;
  if (bi < 256) {
    __shared__ unsigned short tile[64][272];
    int b = bi >> 6, y = bi & 63;
    const float* src = x + (size_t)b * CIN * HW + y * W;
    for (int r = 0; r < 64; ++r) {
      int idx = r * 256 + t;
      int c = idx >> 6, ww = idx & 63;
      tile[ww][c] = f2bf(src[(size_t)c * HW + ww]);
    }
    __syncthreads();
    unsigned short* dst = xT + ((size_t)(b * 64 + y) * 64) * 256;
    for (int r = 0; r < 8; ++r) {
      int idx = r * 2048 + t * 8;
      int ww = idx >> 8, c = idx & 255;
      *(uint4*)(dst + idx) = *(const uint4*)&tile[ww][c];
    }
  } else if (bi < 544) {
    int pkt = (bi - 256) * 256 + t;        // [0, 73728)
    int lane = pkt & 63;
    int tn = (pkt >> 6) & 15;
    int k2 = pkt >> 10;
    int co = tn * 16 + (lane & 15);
    int kb = k2 * 32 + (lane >> 4) * 8;
    unsigned short v[8];
#pragma unroll
    for (int j = 0; j < 8; ++j) {
      int kk = kb + j;
      int kt = kk >> 8, c = kk & 255;
      v[j] = f2bf(w[(co * 256 + c) * 9 + kt]);
    }
    *(uint4*)&wBf[(size_t)pkt * 8] = *(const uint4*)v;
  } else if (bi < 580) {
    int pkt = (bi - 544) * 256 + t;        // [0, 9216)
    int lane = pkt & 63;
    int tn = (pkt >> 6) & 1;
    int k2 = pkt >> 7;
    int oc = tn * 16 + (lane & 15);
    int kb = k2 * 32 + (lane >> 4) * 8;
    unsigned short v[8];
#pragma unroll
    for (int j = 0; j < 8; ++j) {
      int kk = kb + j;
      int kt = kk >> 8, c = kk & 255;
      v[j] = (oc < NOFF) ? f2bf(w_off[(oc * 256 + c) * 9 + kt]) : (unsigned short)0;
    }
    *(uint4*)&wOBf[(size_t)pkt * 8] = *(const uint4*)v;
  } else {
    if (t < 128) gstat[t] = 0.f;
  }
}

// ---------------------------------------------------------------------------
// gemm_fused: producer/consumer wave specialization + XCD swizzle (R17) +
// INLINE OFFCONV (deletes the offconv dispatch + 32 MB om3 round-trip).
// Each block IS an offconv (b,irow) block: preamble computes the 27
// offset/mask channels for its 64 pixels via MFMA — 8 waves as 2 tap-group
// replicas (rep0: kt 0-4, rep1: kt 5-8; 4 waves x 16 pixels each),
// partials summed in LDS omL[2][27][64] by the tap build (which now reads
// LDS instead of 9 scattered global om3 loads per (p,k)).
// Main loop unchanged from R17 (65.7-66.2us verified): producers gather/
// combine 1 phase ahead (L2-hit after swizzle: FETCH 28.9->11.7 MB),
// consumers 32 MFMA + B prefetch; raw s_barrier + lgkmcnt(0) only.
// LDS: tapw 9.2K + tapc 9.2K + At 16K + omL 13.8K = 48.6 KB.
// WRITE_SIZE spill detector: expect ~8.5 MB.
// ---------------------------------------------------------------------------
__global__ __launch_bounds__(512, 1) void gemm_fused_kernel(
    const unsigned short* __restrict__ xT, const unsigned short* __restrict__ wOBf,
    const float* __restrict__ b_off, const unsigned short* __restrict__ wBf,
    const float* __restrict__ bias, unsigned short* __restrict__ cvt,
    float* __restrict__ gstat) {
  __shared__ float tapw[64][KK][4];           // 9.2 KB
  __shared__ int   tapc[64][KK][4];           // 9.2 KB
  __shared__ unsigned short At[2][64 * 64];   // 2 x 8 KB, row pitch 128 B
  __shared__ float omL[2][NOFF][64];          // 13.8 KB: offconv partials
  int bid = blockIdx.x;
  int mt = ((bid & 7) << 5) | (bid >> 3);     // XCD swizzle: XCD = bid&7
  int m0 = mt * 64;
  int b = m0 >> 12;
  int irow = (m0 & 4095) >> 6;                // image row (fixed per tile)
  int t = threadIdx.x;                        // 0..511
  int lane = t & 63, wv = t >> 6;             // wv 0..7
  int lr = lane & 15, lq = lane >> 4;
  const unsigned short* xb = xT + (size_t)b * (HW * 256);

  // ---- inline offconv: 2 replicas x (5|4 taps) x 8 c8 -> omL ----
  {
    int rep = wv >> 2, pw = wv & 3;
    int pcol = pw * 16 + lr;                  // pixel column (A-operand row)
    f32x4 oacc[2] = {};
    int ktlo = rep ? 5 : 0;
    int kthi = rep ? 9 : 5;
    for (int kt = ktlo; kt < kthi; ++kt) {
      int ky = kt / 3, kx = kt % 3;
      int yy = irow - 1 + ky, xx = pcol - 1 + kx;
      bool ok = ((unsigned)yy < 64u) && ((unsigned)xx < 64u);
      const unsigned short* ap = xb + ((ok ? yy * 64 + xx : 0) << 8) + lq * 8;
#pragma unroll
      for (int c8 = 0; c8 < 8; ++c8) {
        uint4 av = uint4{0, 0, 0, 0};
        if (ok) av = *(const uint4*)(ap + c8 * 32);
        int k2 = kt * 8 + c8;
        s16x8 a = __builtin_bit_cast(s16x8, av);
        s16x8 b0 = *(const s16x8*)(wOBf + ((((k2 * 2 + 0) << 6) | lane) << 3));
        s16x8 b1 = *(const s16x8*)(wOBf + ((((k2 * 2 + 1) << 6) | lane) << 3));
        oacc[0] = __builtin_amdgcn_mfma_f32_16x16x32_bf16(a, b0, oacc[0], 0, 0, 0);
        oacc[1] = __builtin_amdgcn_mfma_f32_16x16x32_bf16(a, b1, oacc[1], 0, 0, 0);
      }
    }
#pragma unroll
    for (int tn = 0; tn < 2; ++tn) {
      int oc = tn * 16 + lr;
      if (oc < NOFF) {
#pragma unroll
        for (int r = 0; r < 4; ++r)
          omL[rep][oc][pw * 16 + lq * 4 + r] = oacc[tn][r];
      }
    }
  }
  __syncthreads();

  // ---- tap tables: 64 pixels x 9 taps, from LDS partials ----
  for (int idx = t; idx < 64 * KK; idx += 512) {
    int p = idx / KK, k = idx % KK;
    float offy = omL[0][k][p] + omL[1][k][p] + b_off[k];
    float offx = omL[0][9 + k][p] + omL[1][9 + k][p] + b_off[9 + k];
    float mval = omL[0][18 + k][p] + omL[1][18 + k][p] + b_off[18 + k];
    float mask = 1.f / (1.f + __expf(-mval));
    float py = (float)(irow - 1 + k / 3) + offy;
    float px = (float)(p - 1 + k % 3) + offx;
    float y0f = floorf(py), x0f = floorf(px);
    float wy1 = py - y0f, wx1 = px - x0f;
    int y0 = (int)y0f, x0 = (int)x0f;
    bool y0ok = (unsigned)y0 < 64u, y1ok = (unsigned)(y0 + 1) < 64u;
    bool x0ok = (unsigned)x0 < 64u, x1ok = (unsigned)(x0 + 1) < 64u;
    tapw[p][k][0] = (1.f - wy1) * (1.f - wx1) * mask * (float)(y0ok && x0ok);
    tapw[p][k][1] = (1.f - wy1) * wx1 * mask * (float)(y0ok && x1ok);
    tapw[p][k][2] = wy1 * (1.f - wx1) * mask * (float)(y1ok && x0ok);
    tapw[p][k][3] = wy1 * wx1 * mask * (float)(y1ok && x1ok);
    int y0c = min(max(y0, 0), 63), y1c = min(max(y0 + 1, 0), 63);
    int x0c = min(max(x0, 0), 63), x1c = min(max(x0 + 1, 0), 63);
    tapc[p][k][0] = (y0c * 64 + x0c) * 256;
    tapc[p][k][1] = (x1c - x0c) * 256;
    tapc[p][k][2] = (y1c - y0c) * 64 * 256;
    tapc[p][k][3] = 0;
  }
  __syncthreads();

  // roles: waves 0-3 produce, waves 4-7 consume.
  bool isProd = (wv < 4);
  // producer mapping (threads 0..255): row p = t>>2, octet pair q = t&3
  int p = (t & 255) >> 2, q = t & 3;
  // consumer mapping: cw = wv-4 -> cout block cw*64
  int cw = isProd ? 0 : (wv - 4);
  const unsigned short* bb = wBf + ((size_t)(cw * 4) * 64 + lane) * 8;
  // B addr for (k2, tn): bb + k2*8192 + tn*512

  f32x4 acc[4][4] = {};
  s16x8 Bfa[2][4], Bfb[2][4];
  uint4 sG[8];

#define GLOAD(JJ)                                                            \
  {                                                                          \
    int kt_ = (JJ) >> 2, cg_ = (JJ) & 3;                                     \
    int4 tc_ = *(const int4*)&tapc[p][kt_][0];                               \
    const unsigned short* c_ = xb + tc_.x + cg_ * 64 + q * 16;               \
    sG[0] = *(const uint4*)(c_);                                             \
    sG[1] = *(const uint4*)(c_ + 8);                                         \
    sG[2] = *(const uint4*)(c_ + tc_.y);                                     \
    sG[3] = *(const uint4*)(c_ + tc_.y + 8);                                 \
    sG[4] = *(const uint4*)(c_ + tc_.z);                                     \
    sG[5] = *(const uint4*)(c_ + tc_.z + 8);                                 \
    sG[6] = *(const uint4*)(c_ + tc_.z + tc_.y);                             \
    sG[7] = *(const uint4*)(c_ + tc_.z + tc_.y + 8);                         \
  }

#define COMBINE(JJ, BUFI)                                                    \
  {                                                                          \
    int kt_ = (JJ) >> 2;                                                     \
    f32x4 tw_ = *(const f32x4*)&tapw[p][kt_][0];                             \
    _Pragma("unroll") for (int o = 0; o < 2; ++o) {                          \
      const unsigned* a00_ = (const unsigned*)&sG[0 + o];                    \
      const unsigned* a01_ = (const unsigned*)&sG[2 + o];                    \
      const unsigned* a10_ = (const unsigned*)&sG[4 + o];                    \
      const unsigned* a11_ = (const unsigned*)&sG[6 + o];                    \
      uint4 res_;                                                            \
      unsigned* rr_ = (unsigned*)&res_;                                      \
      _Pragma("unroll") for (int u = 0; u < 4; ++u) {                        \
        float lo_ = tw_[0] * bflo(a00_[u]) + tw_[1] * bflo(a01_[u]) +        \
                    tw_[2] * bflo(a10_[u]) + tw_[3] * bflo(a11_[u]);         \
        float hi_ = tw_[0] * bfhi(a00_[u]) + tw_[1] * bfhi(a01_[u]) +        \
                    tw_[2] * bfhi(a10_[u]) + tw_[3] * bfhi(a11_[u]);         \
        rr_[u] = packbf(lo_, hi_);                                           \
      }                                                                      \
      *(uint4*)((char*)At[BUFI] + p * 128 + (((q * 2 + o) ^ (p & 7)) * 16)) = res_; \
    }                                                                        \
  }

#define BISSUE(J, SLOT)                                                      \
  {                                                                          \
    int k2b_ = (J) * 2;                                                      \
    _Pragma("unroll") for (int kh = 0; kh < 2; ++kh)                         \
      _Pragma("unroll") for (int tn = 0; tn < 4; ++tn)                       \
        SLOT[kh][tn] = *(const s16x8*)(bb + (size_t)(k2b_ + kh) * 8192 + tn * 512); \
  }

#define CONSUME(BUFI, SLOT)                                                  \
  {                                                                          \
    const char* buf_ = (const char*)At[BUFI];                                \
    _Pragma("unroll") for (int kh = 0; kh < 2; ++kh) {                       \
      s16x8 af[4];                                                           \
      _Pragma("unroll") for (int tm = 0; tm < 4; ++tm) {                     \
        int r_ = tm * 16 + lr;                                               \
        af[tm] = *(const s16x8*)(buf_ + r_ * 128 + (((kh * 4 + lq) ^ (r_ & 7)) * 16)); \
      }                                                                      \
      __builtin_amdgcn_s_setprio(1);                                         \
      _Pragma("unroll") for (int tm = 0; tm < 4; ++tm)                       \
        _Pragma("unroll") for (int tn = 0; tn < 4; ++tn)                     \
          acc[tm][tn] = __builtin_amdgcn_mfma_f32_16x16x32_bf16(             \
              af[tm], SLOT[kh][tn], acc[tm][tn], 0, 0, 0);                   \
      __builtin_amdgcn_s_setprio(0);                                         \
    }                                                                        \
  }

#define SOFTBAR()                                                            \
  {                                                                          \
    asm volatile("s_waitcnt lgkmcnt(0)" ::: "memory");                       \
    __builtin_amdgcn_sched_barrier(0);                                       \
    __builtin_amdgcn_s_barrier();                                            \
  }

  // prologue: producers build A(0) into buf0 and issue gathers(1);
  // consumers prefetch B(0)/B(1). Barrier is uniform.
  if (isProd) {
    GLOAD(0);
    COMBINE(0, 0);             // vmcnt auto-wait on gathers(0)
    GLOAD(1);
  } else {
    BISSUE(0, Bfa);
    BISSUE(1, Bfb);
  }
  SOFTBAR();                   // buf0 visible; gathers(1) stay in flight

#pragma unroll 1
  for (int k = 0; k < 36; k += 2) {
    // ---- phase k: producers build k+1 into buf1; consumers eat buf0 ----
    if (isProd) {
      COMBINE(k + 1, 1);                   // k+1 <= 35 always
      if (k + 2 < 36) GLOAD(k + 2);
    } else {
      CONSUME(0, Bfa);
      if (k + 2 < 36) BISSUE(k + 2, Bfa);
    }
    SOFTBAR();
    // ---- phase k+1: producers build k+2 into buf0; consumers eat buf1 ----
    if (isProd) {
      if (k + 2 < 36) COMBINE(k + 2, 0);
      if (k + 3 < 36) GLOAD(k + 3);
    } else {
      CONSUME(1, Bfb);
      if (k + 3 < 36) BISSUE(k + 3, Bfb);
    }
    SOFTBAR();
  }

#undef GLOAD
#undef COMBINE
#undef BISSUE
#undef CONSUME
#undef SOFTBAR

  // epilogue (consumers only, barrier-free):
  // m = m0 + tm*16 + lq*4 + r, co = cw*64 + tn*16 + lr
  if (!isProd) {
    int poff = m0 & 4095;
#pragma unroll
    for (int tn = 0; tn < 4; ++tn) {
      int co = cw * 64 + tn * 16 + lr;
      float bco = bias[co];
      unsigned short* cvb = cvt + (size_t)(b * COUT + co) * HW + poff;
      float sS = 0.f, qq = 0.f;
#pragma unroll
      for (int tm = 0; tm < 4; ++tm) {
        ushort4 st;
#pragma unroll
        for (int r = 0; r < 4; ++r) {
          float v = acc[tm][tn][r] + bco;
          sS += v;
          qq += v * v;
          ((unsigned short*)&st)[r] = f2bf(v);
        }
        *(ushort4*)(cvb + tm * 16 + lq * 4) = st;
      }
#pragma unroll
      for (int off = 32; off > 0; off >>= 1) {
        sS += __shfl_down(sS, off, 64);
        qq += __shfl_down(qq, off, 64);
      }
      if (lane == 0) {
        int g = co >> 4;
        atomicAdd(&gstat[(b * 16 + g) * 2 + 0], sS);
        atomicAdd(&gstat[(b * 16 + g) * 2 + 1], qq);
      }
    }
  }
}

// ---------------------------------------------------------------------------
// gn_apply: normalize bf16 convout -> f32 out. grid 2048. (verified)
// ---------------------------------------------------------------------------
__global__ __launch_bounds__(256) void gn_apply_kernel(
    const unsigned short* __restrict__ convout, const float* __restrict__ gstat,
    const float* __restrict__ gamma, const float* __restrict__ beta,
    float* __restrict__ out) {
  int vid = blockIdx.x * 256 + threadIdx.x;
  int e = vid * 8;
  int b = e >> 20;
  int c = (e >> 12) & 255;
  int g = c >> 4;
  float S = gstat[(b * 16 + g) * 2 + 0];
  float Q = gstat[(b * 16 + g) * 2 + 1];
  float mu = S * (1.f / 65536.f);
  float var = Q * (1.f / 65536.f) - mu * mu;
  float rs = rsqrtf(var + EPS);
  float a = rs * gamma[c];
  float bb = beta[c] - mu * a;
  uint4 v = *(const uint4*)(convout + e);
  const unsigned* u = (const unsigned*)&v;
  float4 o0, o1;
  o0.x = bflo(u[0]) * a + bb;  o0.y = bfhi(u[0]) * a + bb;
  o0.z = bflo(u[1]) * a + bb;  o0.w = bfhi(u[1]) * a + bb;
  o1.x = bflo(u[2]) * a + bb;  o1.y = bfhi(u[2]) * a + bb;
  o1.z = bflo(u[3]) * a + bb;  o1.w = bfhi(u[3]) * a + bb;
  *(float4*)(out + e) = o0;
  *(float4*)(out + e + 4) = o1;
}

// ---------------------------------------------------------------------------
extern "C" void kernel_launch(void* const* d_in, const int* in_sizes, int n_in,
                              void* d_out, int out_size, void* d_ws, size_t ws_size,
                              hipStream_t stream) {
  const float* x      = (const float*)d_in[0];
  const float* w_off  = (const float*)d_in[1];
  const float* b_off  = (const float*)d_in[2];
  const float* weight = (const float*)d_in[3];
  const float* bias   = (const float*)d_in[4];
  const float* gamma  = (const float*)d_in[5];
  const float* beta   = (const float*)d_in[6];
  float* out = (float*)d_out;

  // ws layout: xT | wBf | wOBf | cvt | gstat  (om3 deleted — offconv is
  // now inlined in gemm_fused). cvt must NOT alias xT.
  unsigned short* xT   = (unsigned short*)d_ws;               // 8.39 MB
  unsigned short* wBf  = xT + (size_t)B_ * HW * 256;          // 1.18 MB
  unsigned short* wOBf = wBf + (size_t)COUT * KC;             // 147 KB
  unsigned short* cvt  = wOBf + (size_t)32 * KC;              // 8.39 MB
  float* gstat = (float*)(cvt + (size_t)B_ * HW * COUT);      // 512 B

  prep_kernel<<<dim3(581), dim3(256), 0, stream>>>(x, weight, w_off, xT, wBf, wOBf, gstat);
  gemm_fused_kernel<<<dim3(256), dim3(512), 0, stream>>>(xT, wOBf, b_off, wBf, bias, cvt, gstat);
  gn_apply_kernel<<<dim3(2048), dim3(256), 0, stream>>>(cvt, gstat, gamma, beta, out);
}